// Round 4
// baseline (457.701 us; speedup 1.0000x reference)
//
#include <hip/hip_runtime.h>

typedef unsigned short u16;
typedef unsigned int u32;

#define B_   64
#define C_   256
#define L_   4096
#define NH   8
#define NQ   16
#define DH   32
#define HQ   128
#define FHN  512
#define NKS  4
#define EPS_ 1e-6f

// ---- workspace layout (bytes), ~5.6 MB ----
#define WS_WC    0            // u16 [128][32]               8192
#define WS_SWG   8192         // f32 [128]                    512
#define WS_CB    8704         // f32 [128]                    512
#define WS_VGC   9216         // u16 [256][256]            131072
#define WS_WG1   140288       // f32 [256]                   1024
#define WS_WB1   141312       // f32 [256]                   1024
#define WS_DENP  142336       // f32 [4][8192]             131072
#define WS_SNUP  273408       // f32 [4][8192]             131072
#define WS_A     404480       // f32 [64][128][32]        1048576
#define WS_APART 1453056      // f32 [4][64][128][32]     4194304

typedef __attribute__((ext_vector_type(8))) short bf16x8;
typedef __attribute__((ext_vector_type(4))) float f32x4;

__device__ __forceinline__ u16 f32_to_bf16(float f) {
    u32 u = __float_as_uint(f);
    u32 r = u + 0x7fffu + ((u >> 16) & 1u);   // RNE
    return (u16)(r >> 16);
}
__device__ __forceinline__ float bf16_to_f32(u16 h) {
    return __uint_as_float(((u32)h) << 16);
}
__device__ __forceinline__ u32 pk2(u16 lo, u16 hi) {
    return (u32)lo | ((u32)hi << 16);
}

// ---------------------------------------------------------------------------
// k_prep: wc[hq][32] = bf16(attn_w * gamma_slice); Swg = sum of the bf16 vals
// (fp32) so the mu-correction matches the MFMA operand exactly; Cb = w.beta.
// ---------------------------------------------------------------------------
__global__ __launch_bounds__(256) void k_prep(
    const float* __restrict__ attn_w, const float* __restrict__ gamma,
    const float* __restrict__ beta, u16* __restrict__ wc,
    float* __restrict__ Swg, float* __restrict__ Cb)
{
    int t = threadIdx.x;
    if (t >= HQ) return;
    int h = t >> 4;
    float sw = 0.f, cb = 0.f;
    for (int c = 0; c < DH; c++) {
        float w = attn_w[t * DH + c];
        u16 hb = f32_to_bf16(w * gamma[h * DH + c]);
        wc[t * DH + c] = hb;
        sw += bf16_to_f32(hb);
        cb += w * beta[h * DH + c];
    }
    Swg[t] = sw;
    Cb[t] = cb;
}

// ---------------------------------------------------------------------------
// k_prepv: VGc[e][c] = bf16(val_w[e][c]*gamma[c]) for the epilogue MFMA;
// Wg1[e] = sum_c of the bf16 values (exact mu-cancellation), Wb1[e] = w.beta.
// ---------------------------------------------------------------------------
__global__ __launch_bounds__(256) void k_prepv(
    const float* __restrict__ val_w, const float* __restrict__ gamma,
    const float* __restrict__ beta, u16* __restrict__ VGc,
    float* __restrict__ Wg1, float* __restrict__ Wb1)
{
    int t = threadIdx.x;
    int e = blockIdx.x * 4 + (t >> 6);
    int lane = t & 63;
    float4 w  = *(const float4*)(val_w + (size_t)e * C_ + lane * 4);
    float4 g  = *(const float4*)(gamma + lane * 4);
    float4 bt = *(const float4*)(beta + lane * 4);
    u16 h0 = f32_to_bf16(w.x * g.x);
    u16 h1 = f32_to_bf16(w.y * g.y);
    u16 h2 = f32_to_bf16(w.z * g.z);
    u16 h3 = f32_to_bf16(w.w * g.w);
    uint2 pk;
    pk.x = pk2(h0, h1);
    pk.y = pk2(h2, h3);
    *(uint2*)(VGc + (size_t)e * C_ + lane * 4) = pk;
    float sg = bf16_to_f32(h0) + bf16_to_f32(h1) + bf16_to_f32(h2) + bf16_to_f32(h3);
    float sb = w.x * bt.x + w.y * bt.y + w.z * bt.z + w.w * bt.w;
    #pragma unroll
    for (int off = 1; off < 64; off <<= 1) {
        sg += __shfl_xor(sg, off);
        sb += __shfl_xor(sb, off);
    }
    if (lane == 0) { Wg1[e] = sg; Wb1[e] = sb; }
}

// ---------------------------------------------------------------------------
// k_fused v4: grid (4,64), 1024 threads (16 waves), one block per CU.
// Block owns a 1024-l slice, processed in 16 granules of 64 l (2 chunks).
// KEY CHANGE vs R3: 4 threads per channel each load 64 B contiguous ->
// 256 B per channel-visit (R1/R3 were 128 B) to cut DRAM row activations
// on the 16KB-strided x read (theory: row thrash capped x at ~1.8 TB/s).
// Per granule, 3 phases:
//   A: write XC(g) from pr; stats(g) from XT          | barrier
//   B: logits MFMA(g) -> exp -> EA; cvt; load g+2     | barrier
//   C: GEMM(g) (16 MFMA/wave); write XT(g+1)          | barrier
// acc[2][4] = 32 VGPR/lane -> live ~100 regs, fits 128-cap of 16 waves/CU.
// LDS 85 KB (XT 33.8K | EA 18.4K | XC 32.8K; epilogue P 67.6K reuses pool).
// ---------------------------------------------------------------------------
__global__ __launch_bounds__(1024, 1) void k_fused(
    const float* __restrict__ x, const u16* __restrict__ wc,
    const float* __restrict__ Swg, const float* __restrict__ Cb,
    const u16* __restrict__ VGc, float* __restrict__ Apart,
    float* __restrict__ DenP, float* __restrict__ SnuP)
{
    __shared__ __align__(16) char POOL[84992];
    u16* const XT = (u16*)POOL;            // [64][264]          33792 B
    u16* const EA = (u16*)(POOL + 33792);  // [128][72]          18432 B
    u16* const XC = (u16*)(POOL + 52224);  // [2][256][32] swz   32768 B
    __shared__ float smu[64], srs[64];
    __shared__ float sred[256];
    int t = threadIdx.x;
    int lane = t & 63, w = t >> 6;         // wave 0..15
    int lane15 = lane & 15, quad = lane >> 4;
    int ks = blockIdx.x, b = blockIdx.y;
    int c_own = t & 255, seg = t >> 8;     // 4 threads per channel

    // logits assignment: (head, l-half of granule) per wave
    int h = w & 7, lw = w >> 3;
    bf16x8 af = *(const bf16x8*)(wc + (size_t)(h * 16 + lane15) * DH + quad * 8);
    float swr[4], cbr[4];
    #pragma unroll
    for (int r = 0; r < 4; r++) {
        int hq = h * 16 + quad * 4 + r;
        swr[r] = Swg[hq];
        cbr[r] = Cb[hq];
    }

    // GEMM assignment: wave tile [32 hq][64 c] of Praw[128][256]
    int m0 = (w & 3) * 32, n0 = (w >> 2) * 64;

    const float* xR = x + ((size_t)b * C_ + c_own) * L_ + ks * 1024 + seg * 16;

    float4 fr[4];       // fp32 prefetch: 16 l of channel c_own (64 B contig)
    uint4 pr[2];        // packed bf16 (16 l)
    auto loadregs = [&](int g) {
        #pragma unroll
        for (int i = 0; i < 4; i++) fr[i] = *(const float4*)(xR + g * 64 + i * 4);
    };
    auto cvtregs = [&]() {
        const float* pf = (const float*)fr;
        u16 hb[16];
        #pragma unroll
        for (int e = 0; e < 16; e++) hb[e] = f32_to_bf16(pf[e]);
        #pragma unroll
        for (int i = 0; i < 2; i++) {
            uint4 wd;
            wd.x = pk2(hb[i * 8 + 0], hb[i * 8 + 1]);
            wd.y = pk2(hb[i * 8 + 2], hb[i * 8 + 3]);
            wd.z = pk2(hb[i * 8 + 4], hb[i * 8 + 5]);
            wd.w = pk2(hb[i * 8 + 6], hb[i * 8 + 7]);
            pr[i] = wd;
        }
    };
    auto write_xc = [&]() {
        int cn = seg >> 1, hh = seg & 1;
        #pragma unroll
        for (int i = 0; i < 2; i++) {
            int g8 = hh * 2 + i;
            *(uint4*)&XC[cn * 8192 + c_own * 32 + ((g8 ^ ((c_own >> 1) & 3)) * 8)] = pr[i];
        }
    };
    auto write_xt = [&]() {
        const u16* ph = (const u16*)pr;
        #pragma unroll
        for (int e = 0; e < 16; e++) XT[(seg * 16 + e) * 264 + c_own] = ph[e];
    };

    f32x4 acc[2][4];
    #pragma unroll
    for (int i = 0; i < 2; i++)
        #pragma unroll
        for (int j = 0; j < 4; j++) {
            f32x4 z = {0.f, 0.f, 0.f, 0.f};
            acc[i][j] = z;
        }
    float se[4] = {}, sm[4] = {};

    int l_loc = t >> 4, g16 = t & 15;   // stats: 16 threads per l (64 l)

    loadregs(0);
    cvtregs();          // pr = granule 0
    write_xt();         // XT(0)
    loadregs(1);        // fr = granule 1
    __syncthreads();

    for (int g = 0; g < 16; g++) {
        // ---- phase A: XC(g) from pr; stats(g) from XT ----
        write_xc();
        {
            const u16* row = XT + l_loc * 264 + g16 * 16;
            float s = 0.f, q = 0.f;
            #pragma unroll
            for (int j = 0; j < 2; j++) {
                uint4 v = *(const uint4*)(row + j * 8);
                u32 ww[4] = {v.x, v.y, v.z, v.w};
                #pragma unroll
                for (int e = 0; e < 4; e++) {
                    float f0 = __uint_as_float(ww[e] << 16);
                    float f1 = __uint_as_float(ww[e] & 0xffff0000u);
                    s += f0 + f1;
                    q += f0 * f0 + f1 * f1;
                }
            }
            #pragma unroll
            for (int off = 1; off < 16; off <<= 1) {
                s += __shfl_xor(s, off);
                q += __shfl_xor(q, off);
            }
            if (g16 == 0) {
                float mm = s * (1.f / C_);
                float vv = fmaxf(q * (1.f / C_) - mm * mm, 0.f) + EPS_;
                smu[l_loc] = mm;
                srs[l_loc] = rsqrtf(vv);
            }
        }
        __syncthreads();

        // ---- phase B: logits MFMA -> exp -> EA; cvt + prefetch ----
        #pragma unroll
        for (int half = 0; half < 2; half++) {
            int row = lw * 32 + half * 16 + lane15;
            float m_l = smu[row];
            float r_l = srs[row];
            bf16x8 bfrag = *(const bf16x8*)(XT + row * 264 + h * DH + quad * 8);
            f32x4 z = {0.f, 0.f, 0.f, 0.f};
            f32x4 c4 = __builtin_amdgcn_mfma_f32_16x16x32_bf16(af, bfrag, z, 0, 0, 0);
            #pragma unroll
            for (int r = 0; r < 4; r++) {
                float logit = r_l * (c4[r] - m_l * swr[r]) + cbr[r];
                float e = __expf(logit);     // logits ~N(0,1): no max-sub needed
                float ers = e * r_l;
                EA[(h * 16 + quad * 4 + r) * 72 + lw * 36 + half * 16 + lane15] = f32_to_bf16(ers);
                se[r] += e;
                sm[r] += ers * m_l;
            }
        }
        if (g < 15) cvtregs();          // pr = granule g+1
        if (g < 14) loadregs(g + 2);    // fr = granule g+2
        __syncthreads();

        // ---- phase C: GEMM(g) (both chunks) + stage XT(g+1) ----
        #pragma unroll
        for (int cn = 0; cn < 2; cn++) {
            bf16x8 a0 = *(const bf16x8*)&EA[(m0 + lane15) * 72 + cn * 36 + quad * 8];
            bf16x8 a1 = *(const bf16x8*)&EA[(m0 + 16 + lane15) * 72 + cn * 36 + quad * 8];
            #pragma unroll
            for (int j = 0; j < 4; j++) {
                int row = n0 + j * 16 + lane15;
                bf16x8 bbj = *(const bf16x8*)&XC[cn * 8192 + row * 32 + ((quad ^ ((row >> 1) & 3)) * 8)];
                acc[0][j] = __builtin_amdgcn_mfma_f32_16x16x32_bf16(a0, bbj, acc[0][j], 0, 0, 0);
                acc[1][j] = __builtin_amdgcn_mfma_f32_16x16x32_bf16(a1, bbj, acc[1][j], 0, 0, 0);
            }
        }
        if (g < 15) write_xt();         // XT(g+1)
        __syncthreads();
    }

    // ---- softmax partial sums: lane15 reduce, then cross-lw via sred ----
    #pragma unroll
    for (int r = 0; r < 4; r++) {
        #pragma unroll
        for (int off = 1; off < 16; off <<= 1) {
            se[r] += __shfl_xor(se[r], off);
            sm[r] += __shfl_xor(sm[r], off);
        }
    }
    int hqr = h * 16 + quad * 4;
    if (lane15 == 0 && lw == 1) {
        #pragma unroll
        for (int r = 0; r < 4; r++) {
            sred[hqr + r] = se[r];
            sred[128 + hqr + r] = sm[r];
        }
    }
    __syncthreads();
    if (lane15 == 0 && lw == 0) {
        #pragma unroll
        for (int r = 0; r < 4; r++) {
            int row = b * HQ + hqr + r;
            DenP[ks * (B_ * HQ) + row] = se[r] + sred[hqr + r];
            SnuP[ks * (B_ * HQ) + row] = sm[r] + sred[128 + hqr + r];
        }
    }
    __syncthreads();

    // ---- epilogue: Praw -> bf16 P [128][264] -> MFMA with VGc -> Apart ----
    u16* const P = (u16*)POOL;   // 67584 B, reuses the whole pool
    #pragma unroll
    for (int i = 0; i < 2; i++)
        #pragma unroll
        for (int j = 0; j < 4; j++) {
            int prow = m0 + i * 16 + quad * 4;
            int col = n0 + j * 16 + lane15;
            #pragma unroll
            for (int r = 0; r < 4; r++)
                P[(prow + r) * 264 + col] = f32_to_bf16(acc[i][j][r]);
        }
    __syncthreads();
    {
        int he = w >> 1, dt = w & 1;    // 16 waves = 8 heads x 2 d-tiles
        f32x4 c2 = {0.f, 0.f, 0.f, 0.f};
        #pragma unroll
        for (int kk = 0; kk < 8; kk++) {
            bf16x8 a = *(const bf16x8*)&P[(he * 16 + lane15) * 264 + kk * 32 + quad * 8];
            bf16x8 vg = *(const bf16x8*)(VGc + (size_t)(he * DH + dt * 16 + lane15) * C_ + kk * 32 + quad * 8);
            c2 = __builtin_amdgcn_mfma_f32_16x16x32_bf16(a, vg, c2, 0, 0, 0);
        }
        float* ApB = Apart + (((size_t)ks * B_ + b) * HQ) * DH;
        #pragma unroll
        for (int r = 0; r < 4; r++)
            ApB[(size_t)(he * 16 + quad * 4 + r) * DH + dt * 16 + lane15] = c2[r];
    }
}

// ---------------------------------------------------------------------------
// k_reduce: A[b][hq][d] = (sum_s Apart - SnuTot*Wg1[hd]) / DenTot
//           + Wb1[hd] + val_b[hd]       (beta term: se/den == 1)
// ---------------------------------------------------------------------------
__global__ __launch_bounds__(256) void k_reduce(
    const float* __restrict__ Apart, const float* __restrict__ DenP,
    const float* __restrict__ SnuP, const float* __restrict__ Wg1,
    const float* __restrict__ Wb1, const float* __restrict__ val_b,
    float* __restrict__ A)
{
    __shared__ float sden[32], ssnu[32];
    int t = threadIdx.x;
    int q4 = blockIdx.x, b = blockIdx.y;
    int hq0 = q4 * 32;
    if (t < 32) {
        int row = b * HQ + hq0 + t;
        float d = 0.f, sn = 0.f;
        #pragma unroll
        for (int s = 0; s < NKS; s++) {
            d  += DenP[s * (B_ * HQ) + row];
            sn += SnuP[s * (B_ * HQ) + row];
        }
        sden[t] = d;
        ssnu[t] = sn;
    }
    __syncthreads();
    #pragma unroll
    for (int i = 0; i < 4; i++) {
        int idx = i * 256 + t;
        int r32 = idx >> 5, d = idx & 31;
        int hq = hq0 + r32;
        float v = 0.f;
        #pragma unroll
        for (int s = 0; s < NKS; s++)
            v += Apart[(((size_t)s * B_ + b) * HQ + hq) * DH + d];
        int hd = (hq >> 4) * DH + d;
        A[((size_t)b * HQ + hq) * DH + d] =
            (v - ssnu[r32] * Wg1[hd]) / sden[r32] + Wb1[hd] + val_b[hd];
    }
}

// ---------------------------------------------------------------------------
// k_final: out[b][f] = sum_j A[b][j]*fin_w[f][j] + fin_b[f]
// grid (32,16), block 256; k-split atomicAdd (out pre-zeroed).
// ---------------------------------------------------------------------------
__global__ __launch_bounds__(256) void k_final(
    const float* __restrict__ A, const float* __restrict__ fin_w,
    const float* __restrict__ fin_b, float* __restrict__ out)
{
    __shared__ float At[64 * 129];
    __shared__ float Fw[32 * 129];
    int t = threadIdx.x;
    int kc = blockIdx.x, ft = blockIdx.y;
    int k0 = kc * 128;

    #pragma unroll
    for (int w = 0; w < 8; w++) {
        int s = t + w * 256;
        int row = s >> 5, seg = s & 31;
        float4 v = *(const float4*)(A + (size_t)row * 4096 + k0 + seg * 4);
        const float* pf = (const float*)&v;
        #pragma unroll
        for (int e = 0; e < 4; e++) At[row * 129 + seg * 4 + e] = pf[e];
    }
    #pragma unroll
    for (int w = 0; w < 4; w++) {
        int s = t + w * 256;
        int row = s >> 5, seg = s & 31;
        float4 v = *(const float4*)(fin_w + (size_t)(ft * 32 + row) * 4096 + k0 + seg * 4);
        const float* pf = (const float*)&v;
        #pragma unroll
        for (int e = 0; e < 4; e++) Fw[row * 129 + seg * 4 + e] = pf[e];
    }
    __syncthreads();

    int tb = t >> 3, tf = t & 7;
    float acc[2][4];
    #pragma unroll
    for (int e = 0; e < 2; e++)
        #pragma unroll
        for (int j = 0; j < 4; j++) acc[e][j] = 0.f;

    for (int k = 0; k < 128; k++) {
        float a0 = At[(tb * 2) * 129 + k];
        float a1 = At[(tb * 2 + 1) * 129 + k];
        #pragma unroll
        for (int j = 0; j < 4; j++) {
            float f = Fw[(tf * 4 + j) * 129 + k];
            acc[0][j] += a0 * f;
            acc[1][j] += a1 * f;
        }
    }
    #pragma unroll
    for (int e = 0; e < 2; e++) {
        int brow = tb * 2 + e;
        #pragma unroll
        for (int j = 0; j < 4; j++) {
            int f = ft * 32 + tf * 4 + j;
            float v = acc[e][j];
            if (kc == 0) v += fin_b[f];
            atomicAdd(&out[(size_t)brow * FHN + f], v);
        }
    }
}

extern "C" void kernel_launch(void* const* d_in, const int* in_sizes, int n_in,
                              void* d_out, int out_size, void* d_ws, size_t ws_size,
                              hipStream_t stream) {
    const float* x      = (const float*)d_in[0];
    const float* gamma  = (const float*)d_in[1];
    const float* beta   = (const float*)d_in[2];
    const float* attn_w = (const float*)d_in[3];
    const float* val_w  = (const float*)d_in[4];
    const float* val_b  = (const float*)d_in[5];
    const float* fin_w  = (const float*)d_in[6];
    const float* fin_b  = (const float*)d_in[7];
    float* out = (float*)d_out;
    char* ws = (char*)d_ws;

    u16*   wc    = (u16*)(ws + WS_WC);
    float* Swg   = (float*)(ws + WS_SWG);
    float* Cb    = (float*)(ws + WS_CB);
    u16*   VGc   = (u16*)(ws + WS_VGC);
    float* Wg1   = (float*)(ws + WS_WG1);
    float* Wb1   = (float*)(ws + WS_WB1);
    float* DenP  = (float*)(ws + WS_DENP);
    float* SnuP  = (float*)(ws + WS_SNUP);
    float* A     = (float*)(ws + WS_A);
    float* Apart = (float*)(ws + WS_APART);

    hipMemsetAsync(out, 0, (size_t)B_ * FHN * sizeof(float), stream);

    k_prep<<<dim3(1), dim3(256), 0, stream>>>(attn_w, gamma, beta, wc, Swg, Cb);
    k_prepv<<<dim3(64), dim3(256), 0, stream>>>(val_w, gamma, beta, VGc, Wg1, Wb1);
    k_fused<<<dim3(NKS, 64), dim3(1024), 0, stream>>>(x, wc, Swg, Cb, VGc, Apart,
                                                      DenP, SnuP);
    k_reduce<<<dim3(4, 64), dim3(256), 0, stream>>>(Apart, DenP, SnuP, Wg1, Wb1,
                                                    val_b, A);
    k_final<<<dim3(32, 16), dim3(256), 0, stream>>>(A, fin_w, fin_b, out);
}